// Round 6
// baseline (541.688 us; speedup 1.0000x reference)
//
#include <hip/hip_runtime.h>
#include <hip/hip_bf16.h>
#include <hip/hip_cooperative_groups.h>

namespace cg = cooperative_groups;

// out[b,s,o] = x @ w_eff^T + bias, where
//   w_eff[o][k] = r*lut4[o][c4] + (1-r)*lut5[o][c5],  c5 = 2*c4 + b4
//   combined: lut_c[o][c5] = r*lut4[o][c5>>1] + (1-r)*lut5[o][c5]  (one lookup)
//   r = 2 - 3*sigmoid(z).  M=8192, N=4096, K=4096.
//
// Round 6: ONE cooperative kernel. Phase 1 = cast+dequant (grid-strided),
// grid.sync(), Phase 2 = round-3 GEMM core (16x16x32 MFMA, conflict-free
// XOR swizzle, counted vmcnt, 2 barriers/K-tile), 2 output tiles per block.
// Eliminates the prologue kernel launch + inter-kernel drain (~200 us residual
// candidate). GEMM inner loop is byte-identical to the verified round-3 one.

#define IN_F   4096
#define OUT_F  4096
#define M_DIM  8192   // 4*2048

#define NT (IN_F / 64)     // 64 K-tiles of BK=64
#define TSH (256 * 64)     // shorts per 256x64 tile buffer (32 KB)

typedef __bf16          bf16x8   __attribute__((ext_vector_type(8)));
typedef float           f32x4    __attribute__((ext_vector_type(4)));
typedef unsigned short  ushortx8 __attribute__((ext_vector_type(8)));

__device__ __forceinline__ unsigned short f32_to_bf16(float f) {
    unsigned int u = __builtin_bit_cast(unsigned int, f);
    u += 0x7fffu + ((u >> 16) & 1u);   // RNE (finite values only here)
    return (unsigned short)(u >> 16);
}

__device__ __forceinline__ void async_load16(const void* g, void* l) {
    __builtin_amdgcn_global_load_lds(
        (const __attribute__((address_space(1))) unsigned int*)g,
        (__attribute__((address_space(3))) unsigned int*)l,
        16, 0, 0);
}

// Stage one 128x64 bf16 half-tile: 2 x global_load_lds dwordx4 per thread.
// LDS dest is linear (wave-uniform base + lane*16B); the XOR swizzle is
// pre-applied to the GLOBAL source column (rule #21: swizzle both sides).
__device__ __forceinline__ void stage_half(const unsigned short* g0,
                                           unsigned short* l0) {
    async_load16(g0, l0);
    async_load16(g0 + (size_t)64 * IN_F, l0 + 4096);
}

// ---------------------------------------------------------------------------
// GEMM tile step (round-3 verbatim): 16x16x32 MFMA, 2 barriers per K-tile.
// Per K-tile t (cA=sA[t&1], cB=sB[t&1], nA=sA[(t+1)&1]):
//   half 1: read bf0,bf1 (B kk0,kk1) + A m0-3; stage A(t+1)->nA;
//           MFMA acc[0..3] over kk0,kk1.
//   -- barrier (all B LDS reads of this tile complete; B-stage now safe) --
//   half 2: read A m4-7; stage B(t+2)->cB (B(t) fully in regs);
//           MFMA acc[4..7] over kk0,kk1.
//   -- vmcnt(4) + barrier (completes A(t+1),B(t+1); leaves B(t+2) in flight) --
// vmcnt audit: steady state at boundary: outstanding = B(t+1)[4, oldest] +
// A(t+1)[4] + B(t+2)[4] = 12; vmcnt(4) completes B(t+1)+A(t+1) — exactly what
// tile t+1 reads — never drains to 0 mid-loop.
// ---------------------------------------------------------------------------

#define MFMA_BF16 __builtin_amdgcn_mfma_f32_16x16x32_bf16

__device__ __forceinline__ void tile_step(
    int t,
    const unsigned short* cA, unsigned short* cB, unsigned short* nA,
    int tid,
    const unsigned short* gA0, const unsigned short* gA1,
    const unsigned short* gB0, const unsigned short* gB1,
    int aBase, int bBase, int ck0, int ck1,
    f32x4 (&acc)[8][4])
{
    bf16x8 bf0[4], bf1[4], afa[4], afb[4], afc[4], afd[4];

    // ---------------- half 1: m0-3, kk0+kk1 ----------------
    #pragma unroll
    for (int n = 0; n < 4; ++n)
        bf0[n] = *(const bf16x8*)(cB + bBase + n * 1024 + ck0);
    #pragma unroll
    for (int n = 0; n < 4; ++n)
        bf1[n] = *(const bf16x8*)(cB + bBase + n * 1024 + ck1);
    #pragma unroll
    for (int m = 0; m < 4; ++m)
        afa[m] = *(const bf16x8*)(cA + aBase + m * 1024 + ck0);

    if (t + 1 < NT) {
        stage_half(gA0 + (size_t)(t + 1) * 64, nA + tid * 8);
        stage_half(gA1 + (size_t)(t + 1) * 64, nA + 8192 + tid * 8);
    }

    __builtin_amdgcn_s_setprio(1);
    #pragma unroll
    for (int m = 0; m < 4; ++m)
        #pragma unroll
        for (int n = 0; n < 4; ++n)
            acc[m][n] = MFMA_BF16(afa[m], bf0[n], acc[m][n], 0, 0, 0);
    __builtin_amdgcn_s_setprio(0);

    #pragma unroll
    for (int m = 0; m < 4; ++m)
        afb[m] = *(const bf16x8*)(cA + aBase + m * 1024 + ck1);

    __builtin_amdgcn_s_setprio(1);
    #pragma unroll
    for (int m = 0; m < 4; ++m)
        #pragma unroll
        for (int n = 0; n < 4; ++n)
            acc[m][n] = MFMA_BF16(afb[m], bf1[n], acc[m][n], 0, 0, 0);
    __builtin_amdgcn_s_setprio(0);

    // ---- mid-tile barrier: all waves done with B LDS reads ----
    __builtin_amdgcn_sched_barrier(0);
    __builtin_amdgcn_s_barrier();
    __builtin_amdgcn_sched_barrier(0);

    // ---------------- half 2: m4-7, kk0+kk1 ----------------
    #pragma unroll
    for (int m = 0; m < 4; ++m)
        afc[m] = *(const bf16x8*)(cA + aBase + (m + 4) * 1024 + ck0);

    if (t + 2 < NT) {
        stage_half(gB0 + (size_t)(t + 2) * 64, cB + tid * 8);
        stage_half(gB1 + (size_t)(t + 2) * 64, cB + 8192 + tid * 8);
    }

    __builtin_amdgcn_s_setprio(1);
    #pragma unroll
    for (int m = 0; m < 4; ++m)
        #pragma unroll
        for (int n = 0; n < 4; ++n)
            acc[m + 4][n] = MFMA_BF16(afc[m], bf0[n], acc[m + 4][n], 0, 0, 0);
    __builtin_amdgcn_s_setprio(0);

    #pragma unroll
    for (int m = 0; m < 4; ++m)
        afd[m] = *(const bf16x8*)(cA + aBase + (m + 4) * 1024 + ck1);

    __builtin_amdgcn_s_setprio(1);
    #pragma unroll
    for (int m = 0; m < 4; ++m)
        #pragma unroll
        for (int n = 0; n < 4; ++n)
            acc[m + 4][n] = MFMA_BF16(afd[m], bf1[n], acc[m + 4][n], 0, 0, 0);
    __builtin_amdgcn_s_setprio(0);

    // ---- boundary: counted vmcnt + barrier ----
    __builtin_amdgcn_sched_barrier(0);
    if (t < NT - 2) asm volatile("s_waitcnt vmcnt(4)" ::: "memory");
    else            asm volatile("s_waitcnt vmcnt(0)" ::: "memory");
    __builtin_amdgcn_s_barrier();
    __builtin_amdgcn_sched_barrier(0);
}

// ---------------------------------------------------------------------------
// Fused cooperative kernel: 256 blocks x 512 threads, 1 block/CU (128 KiB LDS).
// ---------------------------------------------------------------------------
__global__ __launch_bounds__(512, 2) void fused_kernel(
    const float* __restrict__ x,           // [M_DIM][IN_F] fp32
    const unsigned int* __restrict__ qw,   // [6][OUT_F][IN_F/32]
    const float* __restrict__ lut4,        // [OUT_F][16]
    const float* __restrict__ lut5,        // [OUT_F][32]
    const float* __restrict__ zp,          // scalar
    const float* __restrict__ bias,        // [OUT_F]
    unsigned short* __restrict__ xb,       // ws: bf16 [M_DIM][IN_F]
    unsigned short* __restrict__ wb,       // ws: bf16 [OUT_F][IN_F]
    float* __restrict__ C)                 // [M_DIM][OUT_F]
{
    __shared__ unsigned short sA[2][TSH];   // 2 x 32 KB
    __shared__ unsigned short sB[2][TSH];   // 2 x 32 KB  (128 KiB total)

    const int tid = threadIdx.x;
    const int b   = blockIdx.x;             // 0..255

    // ================= Phase 1a: cast x fp32 -> bf16 (grid-strided) ========
    // 33.5M elems; each of 131072 threads handles 16 iters x 16 elems.
    #pragma unroll 4
    for (int it = 0; it < 16; ++it) {
        const size_t s = (size_t)it * (256 * 512) + (size_t)b * 512 + tid;
        const f32x4* src = (const f32x4*)(x + s * 16);
        f32x4 a0 = src[0], a1 = src[1], a2 = src[2], a3 = src[3];
        ushortx8 o0, o1;
        #pragma unroll
        for (int e = 0; e < 4; ++e) {
            o0[e]     = f32_to_bf16(a0[e]);
            o0[4 + e] = f32_to_bf16(a1[e]);
            o1[e]     = f32_to_bf16(a2[e]);
            o1[4 + e] = f32_to_bf16(a3[e]);
        }
        ushortx8* dst = (ushortx8*)(xb + s * 16);
        dst[0] = o0;
        dst[1] = o1;
    }

    // ================= Phase 1b: dequant 16 rows per block =================
    {
        float* sc = (float*)&sA[0][0];      // [16][32] combined LUT (2 KB)
        const float z    = zp[0];
        const float sig  = 1.0f / (1.0f + __expf(-z));
        const float rat  = 2.0f - 3.0f * sig;   // r = 1 - (p - 4), p = 3*sig + 3
        const float rati = 1.0f - rat;
        const int lutrow = tid >> 5;        // 0..15
        const int lutc   = tid & 31;
        const int row0   = b * 16;
        sc[lutrow * 32 + lutc] = rat  * lut4[(row0 + lutrow) * 16 + (lutc >> 1)]
                               + rati * lut5[(row0 + lutrow) * 32 + lutc];
        __syncthreads();

        const int PS = OUT_F * (IN_F / 32);
        #pragma unroll 1
        for (int it = 0; it < 4; ++it) {
            const int lidx = it * 512 + tid;          // 0..2047
            const int gid  = b * 2048 + lidx;         // packed-int32 index
            const int lrow = lidx >> 7;               // 0..15 (wave-uniform)

            const unsigned int w0 = qw[0 * PS + gid];
            const unsigned int w1 = qw[1 * PS + gid];
            const unsigned int w2 = qw[2 * PS + gid];
            const unsigned int w3 = qw[3 * PS + gid];
            const unsigned int w4 = qw[4 * PS + gid];

            unsigned short outv[32];
            #pragma unroll
            for (int i = 0; i < 32; ++i) {
                const unsigned c5 = (((w0 >> i) & 1u) << 4) |
                                    (((w1 >> i) & 1u) << 3) |
                                    (((w2 >> i) & 1u) << 2) |
                                    (((w3 >> i) & 1u) << 1) |
                                     ((w4 >> i) & 1u);
                outv[i] = f32_to_bf16(sc[lrow * 32 + c5]);
            }
            ushortx8* dst = (ushortx8*)(wb + (size_t)gid * 32);
            #pragma unroll
            for (int j = 0; j < 4; ++j) {
                ushortx8 v;
                #pragma unroll
                for (int e = 0; e < 8; ++e) v[e] = outv[j * 8 + e];
                dst[j] = v;
            }
        }
        __syncthreads();
    }

    // ================= grid-wide sync (xb/wb visible to all XCDs) ==========
    cg::this_grid().sync();

    // ================= Phase 2: GEMM, 2 tiles per block ====================
    const int l   = tid & 63;
    const int wv  = tid >> 6;   // 0..7
    const int wr  = wv >> 2;    // 0..1  (M half)
    const int wc  = wv & 3;     // 0..3  (N quarter)
    const int l15 = l & 15;
    const int q   = l >> 4;
    const int xm  = l15 & 7;

    // ds_read bases (shorts). Fragment (row, 16B-chunk c) lives at c^(row&7).
    const int aBase = (wr * 128 + l15) * 64;
    const int bBase = (wc * 64  + l15) * 64;
    const int ck0   = ((q)     ^ xm) * 8;
    const int ck1   = ((4 + q) ^ xm) * 8;

    // staging addressing: thread -> (row sr, pre-swizzled chunk) of a half-tile
    const int sr = tid >> 3;                      // 0..63
    const int cx = ((tid & 7) ^ (sr & 7)) * 8;    // element offset in BK

    #pragma unroll 1
    for (int ti = 0; ti < 2; ++ti) {
        // XCD-chunked tile map: block b (XCD b&7) owns tiles [x*64, x*64+64).
        // Bijective over 512 tiles; a block's two tiles share bm (A reuse).
        const int t  = (b & 7) * 64 + (b >> 3) * 2 + ti;
        const int bn = t & 15;    // 0..15  N tiles
        const int bm = t >> 4;    // 0..31  M tiles

        const unsigned short* gA0 = xb + (size_t)(bm * 256 + sr) * IN_F + cx;
        const unsigned short* gA1 = gA0 + (size_t)128 * IN_F;
        const unsigned short* gB0 = wb + (size_t)(bn * 256 + sr) * IN_F + cx;
        const unsigned short* gB1 = gB0 + (size_t)128 * IN_F;

        // Tile prologue: stage A(0), B(0), B(1) (12 ops); vmcnt(4) completes
        // A0,B0 — B(1) stays in flight (steady-state invariant from tile 0).
        stage_half(gA0,      &sA[0][0] + tid * 8);
        stage_half(gA1,      &sA[0][0] + 8192 + tid * 8);
        stage_half(gB0,      &sB[0][0] + tid * 8);
        stage_half(gB1,      &sB[0][0] + 8192 + tid * 8);
        stage_half(gB0 + 64, &sB[1][0] + tid * 8);
        stage_half(gB1 + 64, &sB[1][0] + 8192 + tid * 8);
        asm volatile("s_waitcnt vmcnt(4)" ::: "memory");
        __builtin_amdgcn_s_barrier();
        __builtin_amdgcn_sched_barrier(0);

        f32x4 acc[8][4] = {};

        #pragma unroll 1
        for (int tp = 0; tp < NT; tp += 2) {
            tile_step(tp,     &sA[0][0], &sB[0][0], &sA[1][0], tid,
                      gA0, gA1, gB0, gB1, aBase, bBase, ck0, ck1, acc);
            tile_step(tp + 1, &sA[1][0], &sB[1][0], &sA[0][0], tid,
                      gA0, gA1, gB0, gB1, aBase, bBase, ck0, ck1, acc);
        }

        // Epilogue: C/D layout col = lane&15, row = (lane>>4)*4 + reg
        const int row0 = bm * 256 + wr * 128 + q * 4;
        const int col0 = bn * 256 + wc * 64 + l15;
        #pragma unroll
        for (int n = 0; n < 4; ++n) {
            const float bv = bias[col0 + n * 16];
            #pragma unroll
            for (int m = 0; m < 8; ++m) {
                #pragma unroll
                for (int rr = 0; rr < 4; ++rr)
                    C[(size_t)(row0 + m * 16 + rr) * OUT_F + (col0 + n * 16)] =
                        acc[m][n][rr] + bv;
            }
        }
        // Next tile's staging is safe: all LDS reads of this tile completed
        // before the final vmcnt(0)+barrier inside tile_step(NT-1); the
        // epilogue touches only registers/global.
    }
}

extern "C" void kernel_launch(void* const* d_in, const int* in_sizes, int n_in,
                              void* d_out, int out_size, void* d_ws, size_t ws_size,
                              hipStream_t stream)
{
    const float*        x    = (const float*)d_in[0];        // (4,2048,4096)
    const float*        z    = (const float*)d_in[1];        // scalar
    const float*        lut4 = (const float*)d_in[2];        // (4096,16)
    const float*        lut5 = (const float*)d_in[3];        // (4096,32)
    const float*        bias = (const float*)d_in[4];        // (4096,)
    const unsigned int* qw   = (const unsigned int*)d_in[5]; // (6,4096,128)
    float* out = (float*)d_out;                              // (4,2048,4096)

    unsigned short* xb = (unsigned short*)d_ws;              // bf16, 64 MB
    unsigned short* wb = xb + (size_t)M_DIM * IN_F;          // bf16, 32 MB

    void* args[] = { (void*)&x, (void*)&qw, (void*)&lut4, (void*)&lut5,
                     (void*)&z, (void*)&bias, (void*)&xb, (void*)&wb,
                     (void*)&out };
    hipLaunchCooperativeKernel((const void*)fused_kernel,
                               dim3(256), dim3(512), args, 0, stream);
}